// Round 6
// baseline (342.382 us; speedup 1.0000x reference)
//
#include <hip/hip_runtime.h>
#include <math.h>

#define IN_DIM 128
#define HEADS 8
#define HID 16
#define OUT_DIM 40
#define NEG 0.2f

typedef short bf16x8 __attribute__((ext_vector_type(8)));
typedef float f32x4 __attribute__((ext_vector_type(4)));

__device__ __forceinline__ unsigned short f32_to_bf16_rne(float v) {
  unsigned u = __float_as_uint(v);
  return (unsigned short)((u + 0x7FFFu + ((u >> 16) & 1u)) >> 16);
}

// ---------------- CSR build ----------------

__global__ void zero_ints(int* p, int n) {
  int i = blockIdx.x * blockDim.x + threadIdx.x;
  if (i < n) p[i] = 0;
}

__global__ void hist_k(const int* __restrict__ ei, int E0, int N, int* __restrict__ deg) {
  int e = blockIdx.x * blockDim.x + threadIdx.x;
  int EP = E0 + N;
  if (e >= EP) return;
  int d = (e < E0) ? ei[E0 + e] : (e - E0);
  atomicAdd(&deg[d], 1);
}

__global__ __launch_bounds__(1024) void scanA_k(const int* __restrict__ deg, int* __restrict__ rp,
                                                int* __restrict__ bsum, int n) {
  __shared__ int wsum[16];
  int tid = threadIdx.x;
  int i = blockIdx.x * 1024 + tid;
  int lane = tid & 63, w = tid >> 6;
  int v = (i < n) ? deg[i] : 0;
  int x = v;
  #pragma unroll
  for (int off = 1; off < 64; off <<= 1) {
    int y = __shfl_up(x, off);
    if (lane >= off) x += y;
  }
  if (lane == 63) wsum[w] = x;
  __syncthreads();
  if (tid < 16) {
    int s = wsum[tid];
    #pragma unroll
    for (int off = 1; off < 16; off <<= 1) {
      int y = __shfl_up(s, off);
      if (tid >= off) s += y;
    }
    wsum[tid] = s;
  }
  __syncthreads();
  int woff = (w == 0) ? 0 : wsum[w - 1];
  if (i < n) rp[i] = woff + x - v;
  if (tid == 0) bsum[blockIdx.x] = wsum[15];
}

__global__ __launch_bounds__(1024) void scanB_k(int* __restrict__ bsum, int nb,
                                                int* __restrict__ rp, int n) {
  __shared__ int wsum[16];
  int tid = threadIdx.x;
  int lane = tid & 63, w = tid >> 6;
  int v = (tid < nb) ? bsum[tid] : 0;
  int x = v;
  #pragma unroll
  for (int off = 1; off < 64; off <<= 1) {
    int y = __shfl_up(x, off);
    if (lane >= off) x += y;
  }
  if (lane == 63) wsum[w] = x;
  __syncthreads();
  if (tid < 16) {
    int s = wsum[tid];
    #pragma unroll
    for (int off = 1; off < 16; off <<= 1) {
      int y = __shfl_up(s, off);
      if (tid >= off) s += y;
    }
    wsum[tid] = s;
  }
  __syncthreads();
  int woff = (w == 0) ? 0 : wsum[w - 1];
  if (tid < nb) bsum[tid] = woff + x - v;
  if (tid == 0) rp[n] = wsum[15];
}

__global__ __launch_bounds__(1024) void scanC_k(int* __restrict__ rp, const int* __restrict__ bsum,
                                                int* __restrict__ cnt, int n) {
  int i = blockIdx.x * 1024 + threadIdx.x;
  if (i < n) {
    int v = rp[i] + bsum[blockIdx.x];
    rp[i] = v;
    cnt[i] = v;
  }
}

__global__ void scatter_k(const int* __restrict__ ei, int E0, int N,
                          int* __restrict__ cnt, int* __restrict__ csr_src) {
  int e = blockIdx.x * blockDim.x + threadIdx.x;
  int EP = E0 + N;
  if (e >= EP) return;
  int s, d;
  if (e < E0) { s = ei[e]; d = ei[E0 + e]; } else { s = e - E0; d = s; }
  int pos = atomicAdd(&cnt[d], 1);
  csr_src[pos] = s;
}

// ---------------- W1 pre-pack into MFMA B-fragment order (hi/lo split bf16) ----------------
__global__ void prep_w1_k(const float* __restrict__ W1, const float* __restrict__ as1,
                          const float* __restrict__ ad1,
                          unsigned short* __restrict__ whi, unsigned short* __restrict__ wlo) {
  int t = blockIdx.x * 256 + threadIdx.x;
  if (t >= 9 * 4 * 64 * 8) return;
  int j = t & 7, lane = (t >> 3) & 63, kc = (t >> 9) & 3, ct = t >> 11;
  int k = kc * 32 + (lane >> 4) * 8 + j;
  int col = lane & 15;
  float v;
  if (ct < 8) {
    v = W1[k * 128 + ct * 16 + col];
  } else {
    int h = col & 7;
    const float* att = (col < 8) ? as1 : ad1;
    float s = 0.f;
    #pragma unroll
    for (int d = 0; d < 16; ++d) s += W1[k * 128 + h * 16 + d] * att[h * 16 + d];
    v = s;
  }
  unsigned u = __float_as_uint(v);
  unsigned hi = (u + 0x7FFFu + ((u >> 16) & 1u)) >> 16;
  float rem = v - __uint_as_float(hi << 16);
  unsigned ur = __float_as_uint(rem);
  unsigned lo = (ur + 0x7FFFu + ((ur >> 16) & 1u)) >> 16;
  whi[t] = (unsigned short)hi;
  wlo[t] = (unsigned short)lo;
}

// ---------------- GEMM1 via MFMA (split-bf16), fused a1s/a1d; h1 stored bf16 ----------------
__global__ __launch_bounds__(256) void gemm1_mfma_k(
    const float* __restrict__ x, const unsigned short* __restrict__ whi,
    const unsigned short* __restrict__ wlo,
    unsigned short* __restrict__ h1, float* __restrict__ a1s, float* __restrict__ a1d, int N) {
  int w = threadIdx.x >> 6, lane = threadIdx.x & 63;
  int quad = lane >> 4, l15 = lane & 15;
  int row = blockIdx.x * 64 + w * 16 + l15;
  int rowc = (row < N) ? row : (N - 1);

  f32x4 acc[9];
  #pragma unroll
  for (int t = 0; t < 9; ++t) acc[t] = (f32x4){0.f, 0.f, 0.f, 0.f};

  const float* xr = x + (size_t)rowc * 128 + quad * 8;
  #pragma unroll
  for (int kc = 0; kc < 4; ++kc) {
    f32x4 a0 = *reinterpret_cast<const f32x4*>(xr + kc * 32);
    f32x4 a1 = *reinterpret_cast<const f32x4*>(xr + kc * 32 + 4);
    float av[8] = {a0.x, a0.y, a0.z, a0.w, a1.x, a1.y, a1.z, a1.w};
    bf16x8 ahi, alo;
    #pragma unroll
    for (int j = 0; j < 8; ++j) {
      unsigned u = __float_as_uint(av[j]);
      unsigned hi = (u + 0x7FFFu + ((u >> 16) & 1u)) >> 16;
      float rem = av[j] - __uint_as_float(hi << 16);
      unsigned ur = __float_as_uint(rem);
      unsigned lo = (ur + 0x7FFFu + ((ur >> 16) & 1u)) >> 16;
      ahi[j] = (short)hi;
      alo[j] = (short)lo;
    }
    #pragma unroll
    for (int ct = 0; ct < 9; ++ct) {
      bf16x8 bh = *reinterpret_cast<const bf16x8*>(whi + ((size_t)(ct * 4 + kc) * 64 + lane) * 8);
      bf16x8 bl = *reinterpret_cast<const bf16x8*>(wlo + ((size_t)(ct * 4 + kc) * 64 + lane) * 8);
      acc[ct] = __builtin_amdgcn_mfma_f32_16x16x32_bf16(ahi, bh, acc[ct], 0, 0, 0);
      acc[ct] = __builtin_amdgcn_mfma_f32_16x16x32_bf16(ahi, bl, acc[ct], 0, 0, 0);
      acc[ct] = __builtin_amdgcn_mfma_f32_16x16x32_bf16(alo, bh, acc[ct], 0, 0, 0);
    }
  }
  int rbase = blockIdx.x * 64 + w * 16 + quad * 4;
  #pragma unroll
  for (int reg = 0; reg < 4; ++reg) {
    int r = rbase + reg;
    if (r < N) {
      #pragma unroll
      for (int ct = 0; ct < 8; ++ct)
        h1[(size_t)r * 128 + ct * 16 + l15] = f32_to_bf16_rne(acc[ct][reg]);
      float v = acc[8][reg];
      if (l15 < 8) a1s[r * 8 + l15] = v;
      else         a1d[r * 8 + (l15 - 8)] = v;
    }
  }
}

// ---------------- Layer-1 aggregation: wave-per-node, batched weights ----------------
// Weight phase: 64 lanes = 8 edge-slots x 8 heads, each weight computed ONCE.
// Agg phase: src idx via readlane (SGPR saddr), w via shfl (LDS pipe).
__global__ __launch_bounds__(256) void agg1_k(
    const int* __restrict__ row_ptr, const int* __restrict__ csr_src,
    const float* __restrict__ a1s, const float* __restrict__ a1d,
    const unsigned* __restrict__ h1u, const float* __restrict__ bias1,
    const float* __restrict__ W2, const float* __restrict__ att_s2, const float* __restrict__ att_d2,
    unsigned short* __restrict__ h2, float* __restrict__ a2s, float* __restrict__ a2d, int N) {
  int wid = threadIdx.x >> 6;
  int lane = threadIdx.x & 63;
  int n = blockIdx.x * 4 + wid;
  if (n >= N) return;

  __shared__ float vrow_s[4][128];
  float* vrow = vrow_s[wid];

  int rs = row_ptr[n], re = row_ptr[n + 1];
  int jslot = lane >> 3;   // edge slot in weight phase
  int hw = lane & 7;       // head in weight phase
  int head = lane >> 3;    // head owning dims {2*lane, 2*lane+1}
  float adn = a1d[n * 8 + hw];

  float accx = 0.f, accy = 0.f, sww = 0.f;
  for (int i0 = rs; i0 < re; i0 += 8) {
    int idx = i0 + jslot;
    int sj = csr_src[idx < re ? idx : re - 1];
    float e = a1s[sj * 8 + hw] + adn;
    e = fmaxf(e, NEG * e);
    float w = (idx < re) ? __expf(e) : 0.f;
    sww += w;
    #pragma unroll
    for (int jj = 0; jj < 8; ++jj) {
      if (i0 + jj >= re) break;  // wave-uniform
      int s_u = __builtin_amdgcn_readlane(sj, jj * 8);
      float w_b = __shfl(w, jj * 8 + head);
      unsigned u = h1u[(size_t)s_u * 64 + lane];
      accx += w_b * __uint_as_float(u << 16);
      accy += w_b * __uint_as_float(u & 0xFFFF0000u);
    }
  }
  // reduce sww across the 8 edge-slots (xor bits 3,4,5): lane L -> total for head L&7
  sww += __shfl_xor(sww, 8);
  sww += __shfl_xor(sww, 16);
  sww += __shfl_xor(sww, 32);
  float swh = __shfl(sww, head);  // lane 'head' holds head's total

  float inv = 1.f / (swh + 1e-16f);
  float2 b = *reinterpret_cast<const float2*>(bias1 + 2 * lane);
  float vx = accx * inv + b.x;
  float vy = accy * inv + b.y;
  vx = (vx > 0.f) ? vx : (__expf(vx) - 1.f);
  vy = (vy > 0.f) ? vy : (__expf(vy) - 1.f);
  vrow[2 * lane] = vx;
  vrow[2 * lane + 1] = vy;
  // same-wave LDS write->read: no barrier needed

  float hacc = 0.f;
  int c = lane;
  if (c < OUT_DIM) {
    #pragma unroll 4
    for (int k = 0; k < 128; k += 4) {
      float4 vk = *reinterpret_cast<const float4*>(vrow + k);
      hacc += vk.x * W2[k * OUT_DIM + c] + vk.y * W2[(k + 1) * OUT_DIM + c]
            + vk.z * W2[(k + 2) * OUT_DIM + c] + vk.w * W2[(k + 3) * OUT_DIM + c];
    }
    h2[(size_t)n * OUT_DIM + c] = f32_to_bf16_rne(hacc);
  }
  float vs = (c < OUT_DIM) ? hacc * att_s2[c] : 0.f;
  float vd = (c < OUT_DIM) ? hacc * att_d2[c] : 0.f;
  #pragma unroll
  for (int off = 32; off > 0; off >>= 1) {
    vs += __shfl_xor(vs, off);
    vd += __shfl_xor(vd, off);
  }
  if (lane == 0) { a2s[n] = vs; a2d[n] = vd; }
}

// ---------------- Layer-2 aggregation + log_softmax: batched weights ----------------
// Weight phase: 64 lanes compute 64 edge weights at once (single head).
// Agg phase: s and w broadcast via readlane/shfl per edge.
__global__ __launch_bounds__(256) void agg2_k(
    const int* __restrict__ row_ptr, const int* __restrict__ csr_src,
    const float* __restrict__ a2s, const float* __restrict__ a2d,
    const unsigned short* __restrict__ h2, const float* __restrict__ bias2,
    float* __restrict__ out, int N) {
  int wid = threadIdx.x >> 6;
  int lane = threadIdx.x & 63;
  int n = blockIdx.x * 4 + wid;
  if (n >= N) return;

  int rs = row_ptr[n], re = row_ptr[n + 1];
  float adn = a2d[n];
  bool act = lane < OUT_DIM;
  int c = act ? lane : 0;
  float acc = 0.f, swl = 0.f;
  for (int i0 = rs; i0 < re; i0 += 64) {
    int idx = i0 + lane;
    int sL = csr_src[idx < re ? idx : re - 1];
    float e = a2s[sL] + adn;
    e = fmaxf(e, NEG * e);
    float w = (idx < re) ? __expf(e) : 0.f;
    swl += w;
    int m = re - i0; if (m > 64) m = 64;
    #pragma unroll 4
    for (int jj = 0; jj < m; ++jj) {
      int s_u = __builtin_amdgcn_readlane(sL, jj);
      float w_u = __shfl(w, jj);
      unsigned g = h2[(size_t)s_u * OUT_DIM + c];
      acc += w_u * __uint_as_float(g << 16);
    }
  }
  // total weight across lanes
  #pragma unroll
  for (int off = 32; off > 0; off >>= 1) swl += __shfl_xor(swl, off);

  float v = act ? (acc / (swl + 1e-16f) + bias2[c]) : -1e30f;
  float vm = v;
  #pragma unroll
  for (int off = 32; off > 0; off >>= 1) vm = fmaxf(vm, __shfl_xor(vm, off));
  float ex = act ? __expf(v - vm) : 0.f;
  float es = ex;
  #pragma unroll
  for (int off = 32; off > 0; off >>= 1) es += __shfl_xor(es, off);
  if (act) out[(size_t)n * OUT_DIM + c] = v - vm - __logf(es);
}

// ---------------- launch ----------------

extern "C" void kernel_launch(void* const* d_in, const int* in_sizes, int n_in,
                              void* d_out, int out_size, void* d_ws, size_t ws_size,
                              hipStream_t stream) {
  const float* x   = (const float*)d_in[0];
  const float* W1  = (const float*)d_in[1];
  const float* as1 = (const float*)d_in[2];
  const float* ad1 = (const float*)d_in[3];
  const float* b1  = (const float*)d_in[4];
  const float* W2  = (const float*)d_in[5];
  const float* as2 = (const float*)d_in[6];
  const float* ad2 = (const float*)d_in[7];
  const float* b2  = (const float*)d_in[8];
  const int*   ei  = (const int*)d_in[9];
  int N  = in_sizes[0] / IN_DIM;
  int E0 = in_sizes[9] / 2;
  int EP = E0 + N;
  float* out = (float*)d_out;

  char* ws = (char*)d_ws;
  size_t off = 0;
  auto alloc = [&](size_t bytes) {
    char* p = ws + off;
    off += (bytes + 255) & ~size_t(255);
    return p;
  };
  unsigned short* h1 = (unsigned short*)alloc((size_t)N * 128 * 2);
  float* a1s  = (float*)alloc((size_t)N * 8 * 4);
  float* a1d  = (float*)alloc((size_t)N * 8 * 4);
  unsigned short* h2 = (unsigned short*)alloc((size_t)N * 40 * 2);
  float* a2s  = (float*)alloc((size_t)N * 4);
  float* a2d  = (float*)alloc((size_t)N * 4);
  int*   deg  = (int*)alloc((size_t)N * 4);
  int*   cnt  = (int*)alloc((size_t)N * 4);
  int*   rp   = (int*)alloc((size_t)(N + 4) * 4);
  int*   bsum = (int*)alloc((size_t)1024 * 4);
  int*   csr  = (int*)alloc((size_t)EP * 4);
  unsigned short* whi = (unsigned short*)alloc((size_t)9 * 4 * 64 * 8 * 2);
  unsigned short* wlo = (unsigned short*)alloc((size_t)9 * 4 * 64 * 8 * 2);

  int nb = (N + 1023) / 1024;
  zero_ints<<<(N + 255) / 256, 256, 0, stream>>>(deg, N);
  hist_k<<<(EP + 255) / 256, 256, 0, stream>>>(ei, E0, N, deg);
  scanA_k<<<nb, 1024, 0, stream>>>(deg, rp, bsum, N);
  scanB_k<<<1, 1024, 0, stream>>>(bsum, nb, rp, N);
  scanC_k<<<nb, 1024, 0, stream>>>(rp, bsum, cnt, N);
  scatter_k<<<(EP + 255) / 256, 256, 0, stream>>>(ei, E0, N, cnt, csr);
  prep_w1_k<<<(9 * 4 * 64 * 8 + 255) / 256, 256, 0, stream>>>(W1, as1, ad1, whi, wlo);
  gemm1_mfma_k<<<(N + 63) / 64, 256, 0, stream>>>(x, whi, wlo, h1, a1s, a1d, N);
  agg1_k<<<(N + 3) / 4, 256, 0, stream>>>(rp, csr, a1s, a1d, (const unsigned*)h1, b1, W2, as2, ad2, h2, a2s, a2d, N);
  agg2_k<<<(N + 3) / 4, 256, 0, stream>>>(rp, csr, a2s, a2d, h2, b2, out, N);
}